// Round 1
// baseline (1947.238 us; speedup 1.0000x reference)
//
#include <hip/hip_runtime.h>
#include <math.h>

#define Bdim 8
#define Tdim 12
#define BT   96
#define Ndim 1024
#define Cdim 64
#define Ddim 10

// ---------------------------------------------------------------- supports
__global__ __launch_bounds__(256) void k_supports(
    const float* __restrict__ e1, const float* __restrict__ e2,
    float* __restrict__ S)
{
    int idx = blockIdx.x * 256 + threadIdx.x;   // i*1024 + j
    int i = idx >> 10, j = idx & 1023;
    float s = 0.f;
#pragma unroll
    for (int d = 0; d < Ddim; ++d)
        s += e1[i * Ddim + d] * e2[j * Ddim + d]
           - e2[i * Ddim + d] * e1[j * Ddim + d];
    float v = tanhf(s);
    v = fmaxf(v, 0.f);
    if (i == j) v += 1.f;
    S[idx] = v;
}

// ---------------------------------------------------------------- row softmax
__global__ __launch_bounds__(256) void k_softmax_rows(
    const float* __restrict__ In, float* __restrict__ Out)
{
    int row = blockIdx.x;
    const float* r = In + row * Ndim;
    float* o = Out + row * Ndim;
    __shared__ float red[256];
    float lmax = -INFINITY;
    for (int c = threadIdx.x; c < Ndim; c += 256) lmax = fmaxf(lmax, r[c]);
    red[threadIdx.x] = lmax; __syncthreads();
    for (int s = 128; s > 0; s >>= 1) {
        if (threadIdx.x < s) red[threadIdx.x] = fmaxf(red[threadIdx.x], red[threadIdx.x + s]);
        __syncthreads();
    }
    float m = red[0]; __syncthreads();
    float lsum = 0.f;
    for (int c = threadIdx.x; c < Ndim; c += 256) {
        float e = expf(r[c] - m);
        o[c] = e;
        lsum += e;
    }
    red[threadIdx.x] = lsum; __syncthreads();
    for (int s = 128; s > 0; s >>= 1) {
        if (threadIdx.x < s) red[threadIdx.x] += red[threadIdx.x + s];
        __syncthreads();
    }
    float inv = 1.0f / red[0];
    for (int c = threadIdx.x; c < Ndim; c += 256) o[c] *= inv;
}

// ------------------------------------------- batched  out[bt] = M @ x[bt]
// M: N x N.  X,Y: BT x N x C.  64x64 tile, 256 thr, 4x4 micro.
// mode 0: Y = s*relu(acc)   mode 1: Y = acc   mode 2: Y += s*relu(acc)
__global__ __launch_bounds__(256) void k_gemm_nm(
    const float* __restrict__ M, const float* __restrict__ X,
    float* __restrict__ Y, const float* __restrict__ scale_p, int mode)
{
    __shared__ float Mt[64][17];
    __shared__ float Xt[16][64];
    int bt = blockIdx.z;
    int n0 = blockIdx.x * 64;
    const float* Xb = X + (size_t)bt * Ndim * Cdim;
    int tid = threadIdx.x;
    int tx = tid & 15, ty = tid >> 4;
    float acc[4][4] = {};
    for (int k0 = 0; k0 < Ndim; k0 += 16) {
#pragma unroll
        for (int i = 0; i < 4; ++i)
            Mt[ty + 16 * i][tx] = M[(size_t)(n0 + ty + 16 * i) * Ndim + k0 + tx];
#pragma unroll
        for (int i = 0; i < 4; ++i)
            Xt[(tid >> 6) + 4 * i][tid & 63] =
                Xb[(size_t)(k0 + (tid >> 6) + 4 * i) * Cdim + (tid & 63)];
        __syncthreads();
#pragma unroll
        for (int kk = 0; kk < 16; ++kk) {
            float a[4];
#pragma unroll
            for (int i = 0; i < 4; ++i) a[i] = Mt[ty * 4 + i][kk];
            float4 b4 = *(const float4*)&Xt[kk][tx * 4];
            float b[4] = { b4.x, b4.y, b4.z, b4.w };
#pragma unroll
            for (int i = 0; i < 4; ++i)
#pragma unroll
                for (int j = 0; j < 4; ++j)
                    acc[i][j] += a[i] * b[j];
        }
        __syncthreads();
    }
    float s = scale_p ? scale_p[0] : 1.0f;
    float* Yb = Y + (size_t)bt * Ndim * Cdim;
#pragma unroll
    for (int i = 0; i < 4; ++i) {
        int n = n0 + ty * 4 + i;
#pragma unroll
        for (int j = 0; j < 4; ++j) {
            int c = tx * 4 + j;
            float v = acc[i][j];
            size_t idx = (size_t)n * Cdim + c;
            if (mode == 0)      Yb[idx] = s * fmaxf(v, 0.f);
            else if (mode == 1) Yb[idx] = v;
            else                Yb[idx] += s * fmaxf(v, 0.f);
        }
    }
}

// ------------------------------------------- generic  C = A(MaxK) @ B(KxNb)
__global__ __launch_bounds__(256) void k_gemm_generic(
    const float* __restrict__ A, const float* __restrict__ Bm,
    float* __restrict__ Cm, int K, int Nb)
{
    __shared__ float At[64][17];
    __shared__ float Bt[16][64];
    int c0 = blockIdx.x * 64;
    int r0 = blockIdx.y * 64;
    int tid = threadIdx.x;
    int tx = tid & 15, ty = tid >> 4;
    float acc[4][4] = {};
    for (int k0 = 0; k0 < K; k0 += 16) {
#pragma unroll
        for (int i = 0; i < 4; ++i)
            At[ty + 16 * i][tx] = A[(size_t)(r0 + ty + 16 * i) * K + k0 + tx];
#pragma unroll
        for (int i = 0; i < 4; ++i)
            Bt[(tid >> 6) + 4 * i][tid & 63] =
                Bm[(size_t)(k0 + (tid >> 6) + 4 * i) * Nb + c0 + (tid & 63)];
        __syncthreads();
#pragma unroll
        for (int kk = 0; kk < 16; ++kk) {
            float a[4];
#pragma unroll
            for (int i = 0; i < 4; ++i) a[i] = At[ty * 4 + i][kk];
            float4 b4 = *(const float4*)&Bt[kk][tx * 4];
            float b[4] = { b4.x, b4.y, b4.z, b4.w };
#pragma unroll
            for (int i = 0; i < 4; ++i)
#pragma unroll
                for (int j = 0; j < 4; ++j)
                    acc[i][j] += a[i] * b[j];
        }
        __syncthreads();
    }
#pragma unroll
    for (int i = 0; i < 4; ++i)
#pragma unroll
        for (int j = 0; j < 4; ++j)
            Cm[(size_t)(r0 + ty * 4 + i) * Nb + c0 + tx * 4 + j] = acc[i][j];
}

// ------------------------------------------- spatial attention (flash-style)
// softmax over T is local to each (n,m) pair -> no cross-tile rescaling.
// block: (b, 8 n's). stream m in tiles of 8.
#define NT 8
#define MT 8
#define CP 68   // padded LDS row stride (16B aligned, bank-friendly)
__global__ __launch_bounds__(256) void k_sa(
    const float* __restrict__ X, float* __restrict__ Out,
    const float* __restrict__ beta_p)
{
    __shared__ float q [Tdim][NT][CP];
    __shared__ float kt[Tdim][MT][CP];
    __shared__ float p [Tdim][NT][MT];
    int b  = blockIdx.y;
    int n0 = blockIdx.x * NT;
    int tid = threadIdx.x;
    const float* Xb = X + (size_t)b * Tdim * Ndim * Cdim;

    // load q tile: T*NT*C floats
    for (int f = tid; f < Tdim * NT * Cdim / 4; f += 256) {
        int c4 = f & 15, nn = (f >> 4) & 7, t = f >> 7;
        float4 v = *(const float4*)&Xb[(size_t)t * Ndim * Cdim + (size_t)(n0 + nn) * Cdim + c4 * 4];
        *(float4*)&q[t][nn][c4 * 4] = v;
    }

    float acc[Tdim][2];
#pragma unroll
    for (int t = 0; t < Tdim; ++t) { acc[t][0] = 0.f; acc[t][1] = 0.f; }

    int w = tid >> 6, lane = tid & 63;
    int snn = lane >> 3, smm = lane & 7;        // score assignment
    int pnn = tid >> 5, c0 = (tid & 31) * 2;    // PV assignment

    for (int m0 = 0; m0 < Ndim; m0 += MT) {
        __syncthreads();   // prev PV done before kt overwrite (also covers q 1st iter)
        for (int f = tid; f < Tdim * MT * Cdim / 4; f += 256) {
            int c4 = f & 15, mm = (f >> 4) & 7, t = f >> 7;
            float4 v = *(const float4*)&Xb[(size_t)t * Ndim * Cdim + (size_t)(m0 + mm) * Cdim + c4 * 4];
            *(float4*)&kt[t][mm][c4 * 4] = v;
        }
        __syncthreads();
        // scores: wave w handles t = 3w..3w+2 ; lane -> (snn, smm)
#pragma unroll
        for (int j = 0; j < 3; ++j) {
            int t = w * 3 + j;
            const float* qr = &q[t][snn][0];
            const float* kr = &kt[t][smm][0];
            float s = 0.f;
#pragma unroll
            for (int c = 0; c < Cdim; c += 4) {
                float4 a = *(const float4*)&qr[c];
                float4 bb = *(const float4*)&kr[c];
                s += a.x * bb.x + a.y * bb.y + a.z * bb.z + a.w * bb.w;
            }
            p[t][snn][smm] = s;
        }
        __syncthreads();
        // softmax over t per (nn,mm) pair
        if (tid < 64) {
            int nn = tid >> 3, mm = tid & 7;
            float mx = p[0][nn][mm];
#pragma unroll
            for (int t = 1; t < Tdim; ++t) mx = fmaxf(mx, p[t][nn][mm]);
            float e[Tdim]; float sm = 0.f;
#pragma unroll
            for (int t = 0; t < Tdim; ++t) { e[t] = expf(p[t][nn][mm] - mx); sm += e[t]; }
            float inv = 1.0f / sm;
#pragma unroll
            for (int t = 0; t < Tdim; ++t) p[t][nn][mm] = e[t] * inv;
        }
        __syncthreads();
        // PV: thread -> (pnn, c0,c0+1), all t
#pragma unroll
        for (int t = 0; t < Tdim; ++t) {
#pragma unroll
            for (int mm = 0; mm < MT; ++mm) {
                float pp = p[t][pnn][mm];
                float2 kv = *(const float2*)&kt[t][mm][c0];
                acc[t][0] += pp * kv.x;
                acc[t][1] += pp * kv.y;
            }
        }
    }
    float beta = beta_p[0];
#pragma unroll
    for (int t = 0; t < Tdim; ++t) {
        size_t idx = (((size_t)b * Tdim + t) * Ndim + (n0 + pnn)) * Cdim + c0;
        float2 o = *(float2*)&Out[idx];
        o.x += beta * fmaxf(acc[t][0], 0.f);
        o.y += beta * fmaxf(acc[t][1], 0.f);
        *(float2*)&Out[idx] = o;
    }
}

// ------------------------------------------- per-node gconv epilogue
__global__ __launch_bounds__(256) void k_gconv(
    const float* __restrict__ xg, const float* __restrict__ W,
    const float* __restrict__ bias, float* __restrict__ Out,
    const float* __restrict__ alpha_p)
{
    int n = blockIdx.x;
    __shared__ float Wl[Cdim][Cdim];   // [i][o]
    int tid = threadIdx.x;
    for (int f = tid; f < Cdim * Cdim / 4; f += 256)
        *(float4*)&Wl[0][f * 4] = *(const float4*)&W[(size_t)n * Cdim * Cdim + f * 4];
    int o = tid & 63;
    int btg = tid >> 6;
    float bo = bias[(size_t)n * Cdim + o];
    float alpha = alpha_p[0];
    __syncthreads();
    for (int bt = btg; bt < BT; bt += 4) {
        const float* xr = xg + ((size_t)bt * Ndim + n) * Cdim;
        float acc = bo;
#pragma unroll
        for (int i = 0; i < Cdim; ++i)
            acc += xr[i] * Wl[i][o];
        size_t oidx = ((size_t)bt * Ndim + n) * Cdim + o;
        Out[oidx] += alpha * fmaxf(acc, 0.f);
    }
}

// ---------------------------------------------------------------- launch
extern "C" void kernel_launch(void* const* d_in, const int* in_sizes, int n_in,
                              void* d_out, int out_size, void* d_ws, size_t ws_size,
                              hipStream_t stream)
{
    const float* x     = (const float*)d_in[0];
    const float* e1    = (const float*)d_in[1];
    const float* e2    = (const float*)d_in[2];
    const float* Asym  = (const float*)d_in[3];
    const float* wpool = (const float*)d_in[4];
    const float* bpool = (const float*)d_in[5];
    const float* alpha = (const float*)d_in[6];
    const float* beta  = (const float*)d_in[7];
    const float* gamma = (const float*)d_in[8];
    float* out = (float*)d_out;

    float* ws   = (float*)d_ws;
    float* S    = ws;                               // N*N
    float* A    = S    + Ndim * Ndim;               // N*N
    float* W    = A    + Ndim * Ndim;               // N*C*C
    float* bias = W    + (size_t)Ndim * Cdim * Cdim;// N*C
    float* xg   = bias + Ndim * Cdim;               // BT*N*C   (~50.6 MB total)

    k_supports<<<Ndim * Ndim / 256, 256, 0, stream>>>(e1, e2, S);
    k_softmax_rows<<<Ndim, 256, 0, stream>>>(Asym, A);
    // out = gamma * relu(A @ x)
    k_gemm_nm<<<dim3(Ndim / 64, 1, BT), 256, 0, stream>>>(A, x, out, gamma, 0);
    // xg = supports @ x
    k_gemm_nm<<<dim3(Ndim / 64, 1, BT), 256, 0, stream>>>(S, x, xg, nullptr, 1);
    // W = supports @ weights_pool ; bias = supports @ bias_pool
    k_gemm_generic<<<dim3(Cdim * Cdim / 64, Ndim / 64), 256, 0, stream>>>(S, wpool, W, Ndim, Cdim * Cdim);
    k_gemm_generic<<<dim3(1, Ndim / 64), 256, 0, stream>>>(S, bpool, bias, Ndim, Cdim);
    // out += beta * relu(x_sa)
    k_sa<<<dim3(Ndim / NT, Bdim), 256, 0, stream>>>(x, out, beta);
    // out += alpha * relu(xg @ W[n] + bias[n])
    k_gconv<<<Ndim, 256, 0, stream>>>(xg, W, bias, out, alpha);
}

// Round 2
// 946.453 us; speedup vs baseline: 2.0574x; 2.0574x over previous
//
#include <hip/hip_runtime.h>
#include <math.h>

#define Bdim 8
#define Tdim 12
#define BT   96
#define Ndim 1024
#define Cdim 64
#define Ddim 10

typedef __attribute__((ext_vector_type(4))) float f32x4;
typedef __attribute__((ext_vector_type(8))) short bf16x8;

__device__ inline short f2bf(float f) {
    union { float f; unsigned u; } v; v.f = f;
    return (short)((v.u + 0x8000u) >> 16);   // round-half-up, 2 VALU ops
}

// ---------------------------------------------------------------- supports
__global__ __launch_bounds__(256) void k_supports(
    const float* __restrict__ e1, const float* __restrict__ e2,
    float* __restrict__ S)
{
    int idx = blockIdx.x * 256 + threadIdx.x;   // i*1024 + j
    int i = idx >> 10, j = idx & 1023;
    float s = 0.f;
#pragma unroll
    for (int d = 0; d < Ddim; ++d)
        s += e1[i * Ddim + d] * e2[j * Ddim + d]
           - e2[i * Ddim + d] * e1[j * Ddim + d];
    float v = tanhf(s);
    v = fmaxf(v, 0.f);
    if (i == j) v += 1.f;
    S[idx] = v;
}

// ---------------------------------------------------------------- row softmax
__global__ __launch_bounds__(256) void k_softmax_rows(
    const float* __restrict__ In, float* __restrict__ Out)
{
    int row = blockIdx.x;
    const float* r = In + row * Ndim;
    float* o = Out + row * Ndim;
    __shared__ float red[256];
    float lmax = -INFINITY;
    for (int c = threadIdx.x; c < Ndim; c += 256) lmax = fmaxf(lmax, r[c]);
    red[threadIdx.x] = lmax; __syncthreads();
    for (int s = 128; s > 0; s >>= 1) {
        if (threadIdx.x < s) red[threadIdx.x] = fmaxf(red[threadIdx.x], red[threadIdx.x + s]);
        __syncthreads();
    }
    float m = red[0]; __syncthreads();
    float lsum = 0.f;
    for (int c = threadIdx.x; c < Ndim; c += 256) {
        float e = expf(r[c] - m);
        o[c] = e;
        lsum += e;
    }
    red[threadIdx.x] = lsum; __syncthreads();
    for (int s = 128; s > 0; s >>= 1) {
        if (threadIdx.x < s) red[threadIdx.x] += red[threadIdx.x + s];
        __syncthreads();
    }
    float inv = 1.0f / red[0];
    for (int c = threadIdx.x; c < Ndim; c += 256) o[c] *= inv;
}

// ------------------------------------------- batched  out[bt] = M @ x[bt]
__global__ __launch_bounds__(256) void k_gemm_nm(
    const float* __restrict__ M, const float* __restrict__ X,
    float* __restrict__ Y, const float* __restrict__ scale_p, int mode)
{
    __shared__ float Mt[64][17];
    __shared__ float Xt[16][64];
    int bt = blockIdx.z;
    int n0 = blockIdx.x * 64;
    const float* Xb = X + (size_t)bt * Ndim * Cdim;
    int tid = threadIdx.x;
    int tx = tid & 15, ty = tid >> 4;
    float acc[4][4] = {};
    for (int k0 = 0; k0 < Ndim; k0 += 16) {
#pragma unroll
        for (int i = 0; i < 4; ++i)
            Mt[ty + 16 * i][tx] = M[(size_t)(n0 + ty + 16 * i) * Ndim + k0 + tx];
#pragma unroll
        for (int i = 0; i < 4; ++i)
            Xt[(tid >> 6) + 4 * i][tid & 63] =
                Xb[(size_t)(k0 + (tid >> 6) + 4 * i) * Cdim + (tid & 63)];
        __syncthreads();
#pragma unroll
        for (int kk = 0; kk < 16; ++kk) {
            float a[4];
#pragma unroll
            for (int i = 0; i < 4; ++i) a[i] = Mt[ty * 4 + i][kk];
            float4 b4 = *(const float4*)&Xt[kk][tx * 4];
            float b[4] = { b4.x, b4.y, b4.z, b4.w };
#pragma unroll
            for (int i = 0; i < 4; ++i)
#pragma unroll
                for (int j = 0; j < 4; ++j)
                    acc[i][j] += a[i] * b[j];
        }
        __syncthreads();
    }
    float s = scale_p ? scale_p[0] : 1.0f;
    float* Yb = Y + (size_t)bt * Ndim * Cdim;
#pragma unroll
    for (int i = 0; i < 4; ++i) {
        int n = n0 + ty * 4 + i;
#pragma unroll
        for (int j = 0; j < 4; ++j) {
            int c = tx * 4 + j;
            float v = acc[i][j];
            size_t idx = (size_t)n * Cdim + c;
            if (mode == 0)      Yb[idx] = s * fmaxf(v, 0.f);
            else if (mode == 1) Yb[idx] = v;
            else                Yb[idx] += s * fmaxf(v, 0.f);
        }
    }
}

// ------------------------------------------- generic  C = A(MaxK) @ B(KxNb)
__global__ __launch_bounds__(256) void k_gemm_generic(
    const float* __restrict__ A, const float* __restrict__ Bm,
    float* __restrict__ Cm, int K, int Nb)
{
    __shared__ float At[64][17];
    __shared__ float Bt[16][64];
    int c0 = blockIdx.x * 64;
    int r0 = blockIdx.y * 64;
    int tid = threadIdx.x;
    int tx = tid & 15, ty = tid >> 4;
    float acc[4][4] = {};
    for (int k0 = 0; k0 < K; k0 += 16) {
#pragma unroll
        for (int i = 0; i < 4; ++i)
            At[ty + 16 * i][tx] = A[(size_t)(r0 + ty + 16 * i) * K + k0 + tx];
#pragma unroll
        for (int i = 0; i < 4; ++i)
            Bt[(tid >> 6) + 4 * i][tid & 63] =
                Bm[(size_t)(k0 + (tid >> 6) + 4 * i) * Nb + c0 + (tid & 63)];
        __syncthreads();
#pragma unroll
        for (int kk = 0; kk < 16; ++kk) {
            float a[4];
#pragma unroll
            for (int i = 0; i < 4; ++i) a[i] = At[ty * 4 + i][kk];
            float4 b4 = *(const float4*)&Bt[kk][tx * 4];
            float b[4] = { b4.x, b4.y, b4.z, b4.w };
#pragma unroll
            for (int i = 0; i < 4; ++i)
#pragma unroll
                for (int j = 0; j < 4; ++j)
                    acc[i][j] += a[i] * b[j];
        }
        __syncthreads();
    }
#pragma unroll
    for (int i = 0; i < 4; ++i)
#pragma unroll
        for (int j = 0; j < 4; ++j)
            Cm[(size_t)(r0 + ty * 4 + i) * Nb + c0 + tx * 4 + j] = acc[i][j];
}

// ------------------------------------------- spatial attention via MFMA
// Softmax is over T (local per (n,m)) and the MFMA C/D layout is identical
// across t -> one LDS round-trip per m-tile does softmax + layout transform.
// Block: (b, 16 n's); 4 waves x 3 t's; m streamed in 32-tiles.
// grid (b fastest) => XCD round-robin pins one b (3.1 MB) per XCD L2.
#define NT2 16
#define MT2 32
#define PPAD 8
__global__ __launch_bounds__(256) void k_sa_mfma(
    const float* __restrict__ X, float* __restrict__ Out,
    const float* __restrict__ beta_p)
{
    __shared__ float Sb[Tdim][MT2][NT2];            // 24 KB, S^T tile (m,n)
    __shared__ short Pb[Tdim][NT2][MT2 + PPAD];     // 15.4 KB, A-frag layout

    int b  = blockIdx.x;
    int n0 = blockIdx.y * NT2;
    int tid = threadIdx.x;
    int w = tid >> 6, l = tid & 63;
    int l15 = l & 15, q = l >> 4;

    const float* Xb = X + (size_t)b * Tdim * Ndim * Cdim;

    // Q B-fragments (per-wave t's), cached across the m loop.
    // B[k=c][col=n]: lane holds Q[n0+l15][ch*32 + q*8 + e]
    bf16x8 qf[3][2];
#pragma unroll
    for (int j = 0; j < 3; ++j) {
        int t = w * 3 + j;
        const float* base = Xb + ((size_t)t * Ndim + n0 + l15) * Cdim + q * 8;
#pragma unroll
        for (int ch = 0; ch < 2; ++ch) {
            const float* p = base + ch * 32;
            bf16x8 f;
#pragma unroll
            for (int e = 0; e < 8; ++e) f[e] = f2bf(p[e]);
            qf[j][ch] = f;
        }
    }

    f32x4 oacc[3][4];
#pragma unroll
    for (int j = 0; j < 3; ++j)
#pragma unroll
        for (int ct = 0; ct < 4; ++ct) oacc[j][ct] = (f32x4)0.f;

    for (int m0 = 0; m0 < Ndim; m0 += MT2) {
        // ---- scores: S_t[m][n] = K_tile @ Q^T  (contraction over c)
        f32x4 sacc[3][2];
#pragma unroll
        for (int j = 0; j < 3; ++j) { sacc[j][0] = (f32x4)0.f; sacc[j][1] = (f32x4)0.f; }
#pragma unroll
        for (int j = 0; j < 3; ++j) {
            int t = w * 3 + j;
#pragma unroll
            for (int mh = 0; mh < 2; ++mh) {
                const float* abase = Xb + ((size_t)t * Ndim + m0 + mh * 16 + l15) * Cdim + q * 8;
#pragma unroll
                for (int ch = 0; ch < 2; ++ch) {
                    const float* p = abase + ch * 32;
                    bf16x8 af;
#pragma unroll
                    for (int e = 0; e < 8; ++e) af[e] = f2bf(p[e]);
                    sacc[j][mh] = __builtin_amdgcn_mfma_f32_16x16x32_bf16(
                        af, qf[j][ch], sacc[j][mh], 0, 0, 0);
                }
            }
        }
        // C/D: row = q*4+r (m-local), col = l15 (n-local)
#pragma unroll
        for (int j = 0; j < 3; ++j)
#pragma unroll
            for (int mh = 0; mh < 2; ++mh)
#pragma unroll
                for (int r = 0; r < 4; ++r)
                    Sb[w * 3 + j][mh * 16 + q * 4 + r][l15] = sacc[j][mh][r];
        __syncthreads();

        // ---- softmax over t, 512 (m,n) pairs, 2 per thread
#pragma unroll
        for (int p = 0; p < 2; ++p) {
            int idx = p * 256 + tid;
            int m = idx >> 4, n = idx & 15;
            float v[Tdim];
            float mx = -INFINITY;
#pragma unroll
            for (int t = 0; t < Tdim; ++t) { v[t] = Sb[t][m][n]; mx = fmaxf(mx, v[t]); }
            float sm = 0.f;
#pragma unroll
            for (int t = 0; t < Tdim; ++t) { v[t] = expf(v[t] - mx); sm += v[t]; }
            float inv = 1.0f / sm;
#pragma unroll
            for (int t = 0; t < Tdim; ++t) Pb[t][n][m] = f2bf(v[t] * inv);
        }
        __syncthreads();

        // ---- PV: O_t[n][c] += P_t[n][m-tile] @ K_tile[m][c]
#pragma unroll
        for (int j = 0; j < 3; ++j) {
            int t = w * 3 + j;
            bf16x8 pf = *(bf16x8*)&Pb[t][l15][q * 8];       // A[row=n][k=m]
#pragma unroll
            for (int ct = 0; ct < 4; ++ct) {
                // B[k=m][col=c]: lane c = ct*16+l15, m = m0+q*8+e (stride-64 f32)
                const float* p = Xb + ((size_t)t * Ndim + m0 + q * 8) * Cdim + ct * 16 + l15;
                bf16x8 bfr;
#pragma unroll
                for (int e = 0; e < 8; ++e) bfr[e] = f2bf(p[e * Cdim]);
                oacc[j][ct] = __builtin_amdgcn_mfma_f32_16x16x32_bf16(
                    pf, bfr, oacc[j][ct], 0, 0, 0);
            }
        }
        // next iter's S-writes touch Sb (not Pb) and are followed by a
        // barrier before softmax reads -> 2 barriers/iter suffice
    }

    float beta = beta_p[0];
#pragma unroll
    for (int j = 0; j < 3; ++j) {
        int t = w * 3 + j;
#pragma unroll
        for (int ct = 0; ct < 4; ++ct) {
#pragma unroll
            for (int r = 0; r < 4; ++r) {
                size_t idx = (((size_t)b * Tdim + t) * Ndim + n0 + q * 4 + r) * Cdim
                           + ct * 16 + l15;
                Out[idx] += beta * fmaxf(oacc[j][ct][r], 0.f);
            }
        }
    }
}

// ------------------------------------------- per-node gconv epilogue
__global__ __launch_bounds__(256) void k_gconv(
    const float* __restrict__ xg, const float* __restrict__ W,
    const float* __restrict__ bias, float* __restrict__ Out,
    const float* __restrict__ alpha_p)
{
    int n = blockIdx.x;
    __shared__ float Wl[Cdim][Cdim];   // [i][o]
    int tid = threadIdx.x;
    for (int f = tid; f < Cdim * Cdim / 4; f += 256)
        *(float4*)&Wl[0][f * 4] = *(const float4*)&W[(size_t)n * Cdim * Cdim + f * 4];
    int o = tid & 63;
    int btg = tid >> 6;
    float bo = bias[(size_t)n * Cdim + o];
    float alpha = alpha_p[0];
    __syncthreads();
    for (int bt = btg; bt < BT; bt += 4) {
        const float* xr = xg + ((size_t)bt * Ndim + n) * Cdim;
        float acc = bo;
#pragma unroll
        for (int i = 0; i < Cdim; ++i)
            acc += xr[i] * Wl[i][o];
        size_t oidx = ((size_t)bt * Ndim + n) * Cdim + o;
        Out[oidx] += alpha * fmaxf(acc, 0.f);
    }
}

// ---------------------------------------------------------------- launch
extern "C" void kernel_launch(void* const* d_in, const int* in_sizes, int n_in,
                              void* d_out, int out_size, void* d_ws, size_t ws_size,
                              hipStream_t stream)
{
    const float* x     = (const float*)d_in[0];
    const float* e1    = (const float*)d_in[1];
    const float* e2    = (const float*)d_in[2];
    const float* Asym  = (const float*)d_in[3];
    const float* wpool = (const float*)d_in[4];
    const float* bpool = (const float*)d_in[5];
    const float* alpha = (const float*)d_in[6];
    const float* beta  = (const float*)d_in[7];
    const float* gamma = (const float*)d_in[8];
    float* out = (float*)d_out;

    float* ws   = (float*)d_ws;
    float* S    = ws;                               // N*N
    float* A    = S    + Ndim * Ndim;               // N*N
    float* W    = A    + Ndim * Ndim;               // N*C*C
    float* bias = W    + (size_t)Ndim * Cdim * Cdim;// N*C
    float* xg   = bias + Ndim * Cdim;               // BT*N*C

    k_supports<<<Ndim * Ndim / 256, 256, 0, stream>>>(e1, e2, S);
    k_softmax_rows<<<Ndim, 256, 0, stream>>>(Asym, A);
    // out = gamma * relu(A @ x)
    k_gemm_nm<<<dim3(Ndim / 64, 1, BT), 256, 0, stream>>>(A, x, out, gamma, 0);
    // xg = supports @ x
    k_gemm_nm<<<dim3(Ndim / 64, 1, BT), 256, 0, stream>>>(S, x, xg, nullptr, 1);
    // W = supports @ weights_pool ; bias = supports @ bias_pool
    k_gemm_generic<<<dim3(Cdim * Cdim / 64, Ndim / 64), 256, 0, stream>>>(S, wpool, W, Ndim, Cdim * Cdim);
    k_gemm_generic<<<dim3(1, Ndim / 64), 256, 0, stream>>>(S, bpool, bias, Ndim, Cdim);
    // out += beta * relu(x_sa)
    k_sa_mfma<<<dim3(Bdim, Ndim / NT2), 256, 0, stream>>>(x, out, beta);
    // out += alpha * relu(xg @ W[n] + bias[n])
    k_gconv<<<Ndim, 256, 0, stream>>>(xg, W, bias, out, alpha);
}

// Round 3
// 490.513 us; speedup vs baseline: 3.9698x; 1.9295x over previous
//
#include <hip/hip_runtime.h>
#include <math.h>

#define Bdim 8
#define Tdim 12
#define BT   96
#define Ndim 1024
#define Cdim 64
#define Ddim 10
#define Jdim 6144      // BT*C
#define IOdim 4096     // C*C

typedef __attribute__((ext_vector_type(4))) float f32x4;
typedef __attribute__((ext_vector_type(8))) short bf16x8;

__device__ inline short f2bf(float f) {
    union { float f; unsigned u; } v; v.f = f;
    return (short)((v.u + 0x8000u) >> 16);
}
__device__ inline float bf2f(short s) {
    union { float f; unsigned u; } v; v.u = ((unsigned)(unsigned short)s) << 16;
    return v.f;
}
__device__ inline void load_lds16(const void* g, void* l) {
    __builtin_amdgcn_global_load_lds(
        (const __attribute__((address_space(1))) unsigned int*)g,
        (__attribute__((address_space(3))) unsigned int*)l, 16, 0, 0);
}

// ---------------------------------------------------------------- supports (bf16)
__global__ __launch_bounds__(256) void k_supports(
    const float* __restrict__ e1, const float* __restrict__ e2,
    short* __restrict__ Sbf)
{
    int idx = blockIdx.x * 256 + threadIdx.x;
    int i = idx >> 10, j = idx & 1023;
    float s = 0.f;
#pragma unroll
    for (int d = 0; d < Ddim; ++d)
        s += e1[i * Ddim + d] * e2[j * Ddim + d]
           - e2[i * Ddim + d] * e1[j * Ddim + d];
    float v = fmaxf(tanhf(s), 0.f);
    if (i == j) v += 1.f;
    Sbf[idx] = f2bf(v);
}

// ---------------------------------------------------------------- row softmax (bf16 out)
__global__ __launch_bounds__(256) void k_softmax_rows(
    const float* __restrict__ In, short* __restrict__ Out)
{
    int row = blockIdx.x;
    const float* r = In + (size_t)row * Ndim;
    short* o = Out + (size_t)row * Ndim;
    __shared__ float red[256];
    int tid = threadIdx.x;
    float vals[4];
    float lmax = -INFINITY;
#pragma unroll
    for (int i = 0; i < 4; ++i) { vals[i] = r[tid + 256 * i]; lmax = fmaxf(lmax, vals[i]); }
    red[tid] = lmax; __syncthreads();
    for (int s = 128; s > 0; s >>= 1) {
        if (tid < s) red[tid] = fmaxf(red[tid], red[tid + s]);
        __syncthreads();
    }
    float m = red[0]; __syncthreads();
    float lsum = 0.f;
#pragma unroll
    for (int i = 0; i < 4; ++i) { vals[i] = expf(vals[i] - m); lsum += vals[i]; }
    red[tid] = lsum; __syncthreads();
    for (int s = 128; s > 0; s >>= 1) {
        if (tid < s) red[tid] += red[tid + s];
        __syncthreads();
    }
    float inv = 1.0f / red[0];
#pragma unroll
    for (int i = 0; i < 4; ++i) o[tid + 256 * i] = f2bf(vals[i] * inv);
}

// ---------------------------------------------------------------- x -> xbf + xT bf16
__global__ __launch_bounds__(256) void k_cvt_x(
    const float* __restrict__ x, short* __restrict__ xbf, short* __restrict__ xT)
{
    __shared__ float Lt[64][65];
    int bt = blockIdx.y, n0 = blockIdx.x * 64;
    const float* src = x + (size_t)bt * 65536 + (size_t)n0 * 64;
    int tid = threadIdx.x;
#pragma unroll
    for (int p = 0; p < 4; ++p) {
        int idx = p * 256 + tid;
        int r = idx >> 4, c4 = idx & 15;
        float4 v = *(const float4*)&src[r * 64 + c4 * 4];
        short4 s4 = make_short4(f2bf(v.x), f2bf(v.y), f2bf(v.z), f2bf(v.w));
        *(short4*)&xbf[(size_t)bt * 65536 + (size_t)(n0 + r) * 64 + c4 * 4] = s4;
        Lt[r][c4 * 4 + 0] = v.x; Lt[r][c4 * 4 + 1] = v.y;
        Lt[r][c4 * 4 + 2] = v.z; Lt[r][c4 * 4 + 3] = v.w;
    }
    __syncthreads();
#pragma unroll
    for (int p = 0; p < 4; ++p) {
        int idx = p * 256 + tid;
        int c = idx >> 4, k4 = idx & 15;
        short4 s4 = make_short4(f2bf(Lt[k4 * 4 + 0][c]), f2bf(Lt[k4 * 4 + 1][c]),
                                f2bf(Lt[k4 * 4 + 2][c]), f2bf(Lt[k4 * 4 + 3][c]));
        *(short4*)&xT[(size_t)bt * 65536 + (size_t)c * 1024 + n0 + k4 * 4] = s4;
    }
}

// ---------------------------------------------------------------- wpool -> wpT bf16 (4096x1024)
__global__ __launch_bounds__(256) void k_cvt_wp(
    const float* __restrict__ wp, short* __restrict__ wpT)
{
    __shared__ float Lt[64][65];
    int k0 = blockIdx.y * 64, j0 = blockIdx.x * 64;
    int tid = threadIdx.x;
#pragma unroll
    for (int p = 0; p < 4; ++p) {
        int idx = p * 256 + tid;
        int r = idx >> 4, c4 = idx & 15;
        float4 v = *(const float4*)&wp[(size_t)(k0 + r) * IOdim + j0 + c4 * 4];
        Lt[r][c4 * 4 + 0] = v.x; Lt[r][c4 * 4 + 1] = v.y;
        Lt[r][c4 * 4 + 2] = v.z; Lt[r][c4 * 4 + 3] = v.w;
    }
    __syncthreads();
#pragma unroll
    for (int p = 0; p < 4; ++p) {
        int idx = p * 256 + tid;
        int c = idx >> 4, k4 = idx & 15;
        short4 s4 = make_short4(f2bf(Lt[k4 * 4 + 0][c]), f2bf(Lt[k4 * 4 + 1][c]),
                                f2bf(Lt[k4 * 4 + 2][c]), f2bf(Lt[k4 * 4 + 3][c]));
        *(short4*)&wpT[(size_t)(j0 + c) * 1024 + k0 + k4 * 4] = s4;
    }
}

// ---------------------------------------------------------------- m97-style bf16 GEMM, C = A @ B^T
// MODE 0: rows<1024 -> out = gamma*relu (f32, scatter to (bt,n,c)); rows>=1024 -> xgT bf16 (stride 6144)
// MODE 1: -> Wbf bf16 (stride 4096)
template<int MODE>
__global__ __launch_bounds__(256) void k_gemm_bt(
    const short* __restrict__ A, const short* __restrict__ Bm,
    float* __restrict__ Cf, short* __restrict__ Cb,
    const float* __restrict__ gamma_p)
{
    __shared__ short At[128 * 64];
    __shared__ short Bt[128 * 64];
    const int tid = threadIdx.x;
    const int w = tid >> 6, l = tid & 63;
    const int l15 = l & 15, q = l >> 4;
    const int n0 = blockIdx.x * 128, j0 = blockIdx.y * 128;
    const int wr = (w & 1) * 64, wc = (w >> 1) * 64;
    const int lrow = l >> 3, lc8 = l & 7;

    f32x4 acc[4][4];
#pragma unroll
    for (int i = 0; i < 4; ++i)
#pragma unroll
        for (int j = 0; j < 4; ++j) acc[i][j] = (f32x4)0.f;

    for (int k0 = 0; k0 < 1024; k0 += 64) {
        __syncthreads();
#pragma unroll
        for (int p = 0; p < 4; ++p) {
            int r = p * 32 + w * 8 + lrow;
            int sc = lc8 ^ (r & 7);
            load_lds16(A + (size_t)(n0 + r) * 1024 + k0 + sc * 8,
                       &At[(p * 32 + w * 8) * 64]);
            load_lds16(Bm + (size_t)(j0 + r) * 1024 + k0 + sc * 8,
                       &Bt[(p * 32 + w * 8) * 64]);
        }
        __syncthreads();
#pragma unroll
        for (int ks = 0; ks < 2; ++ks) {
            bf16x8 af[4], bf[4];
#pragma unroll
            for (int rt = 0; rt < 4; ++rt) {
                int row = wr + rt * 16 + l15;
                int pos = (ks * 4 + q) ^ (row & 7);
                af[rt] = *(const bf16x8*)&At[row * 64 + pos * 8];
            }
#pragma unroll
            for (int ct = 0; ct < 4; ++ct) {
                int row = wc + ct * 16 + l15;
                int pos = (ks * 4 + q) ^ (row & 7);
                bf[ct] = *(const bf16x8*)&Bt[row * 64 + pos * 8];
            }
#pragma unroll
            for (int rt = 0; rt < 4; ++rt)
#pragma unroll
                for (int ct = 0; ct < 4; ++ct)
                    acc[rt][ct] = __builtin_amdgcn_mfma_f32_16x16x32_bf16(
                        af[rt], bf[ct], acc[rt][ct], 0, 0, 0);
        }
    }

    float gmm = (MODE == 0) ? gamma_p[0] : 0.f;
#pragma unroll
    for (int rt = 0; rt < 4; ++rt) {
        int nr = n0 + wr + rt * 16 + q * 4;
#pragma unroll
        for (int ct = 0; ct < 4; ++ct) {
            int j = j0 + wc + ct * 16 + l15;
#pragma unroll
            for (int r = 0; r < 4; ++r) {
                float v = acc[rt][ct][r];
                int n = nr + r;
                if (MODE == 1) {
                    Cb[(size_t)n * IOdim + j] = f2bf(v);
                } else if (n < 1024) {
                    int bt = j >> 6, c = j & 63;
                    Cf[(size_t)bt * 65536 + (size_t)n * 64 + c] = gmm * fmaxf(v, 0.f);
                } else {
                    Cb[(size_t)(n - 1024) * Jdim + j] = f2bf(v);
                }
            }
        }
    }
}

// ---------------------------------------------------------------- spatial attention (bf16 in)
#define NT2 16
#define MT2 32
__global__ __launch_bounds__(256) void k_sa_mfma(
    const short* __restrict__ xbf, const short* __restrict__ xT,
    float* __restrict__ Out, const float* __restrict__ beta_p)
{
    __shared__ float Sb[Tdim][16][36];   // [t][n][m], m-contig; 27.6 KB
    __shared__ short Pb[Tdim][16][40];   // [t][n][m], A-frag layout; 15.4 KB

    int b  = blockIdx.x;
    int n0 = blockIdx.y * NT2;
    int tid = threadIdx.x;
    int w = tid >> 6, l = tid & 63;
    int l15 = l & 15, q = l >> 4;

    const short* Xb = xbf + (size_t)b * Tdim * Ndim * Cdim;
    const short* XT = xT  + (size_t)b * Tdim * Ndim * Cdim;

    // Q B-fragments, cached across the m loop
    bf16x8 qf[3][2];
#pragma unroll
    for (int j = 0; j < 3; ++j) {
        int t = w * 3 + j;
        const short* base = Xb + ((size_t)t * Ndim + n0 + l15) * Cdim + q * 8;
#pragma unroll
        for (int ch = 0; ch < 2; ++ch)
            qf[j][ch] = *(const bf16x8*)(base + ch * 32);
    }

    f32x4 oacc[3][4];
#pragma unroll
    for (int j = 0; j < 3; ++j)
#pragma unroll
        for (int ct = 0; ct < 4; ++ct) oacc[j][ct] = (f32x4)0.f;

    int sn = tid & 15, sm2 = tid >> 4;   // softmax: (n, m-pair)

    for (int m0 = 0; m0 < Ndim; m0 += MT2) {
        // ---- scores
        f32x4 sacc[3][2];
#pragma unroll
        for (int j = 0; j < 3; ++j) { sacc[j][0] = (f32x4)0.f; sacc[j][1] = (f32x4)0.f; }
#pragma unroll
        for (int j = 0; j < 3; ++j) {
            int t = w * 3 + j;
#pragma unroll
            for (int mh = 0; mh < 2; ++mh) {
                const short* ab = Xb + ((size_t)t * Ndim + m0 + mh * 16 + l15) * Cdim + q * 8;
#pragma unroll
                for (int ch = 0; ch < 2; ++ch) {
                    bf16x8 af = *(const bf16x8*)(ab + ch * 32);
                    sacc[j][mh] = __builtin_amdgcn_mfma_f32_16x16x32_bf16(
                        af, qf[j][ch], sacc[j][mh], 0, 0, 0);
                }
            }
        }
#pragma unroll
        for (int j = 0; j < 3; ++j)
#pragma unroll
            for (int mh = 0; mh < 2; ++mh)
                *(f32x4*)&Sb[w * 3 + j][l15][mh * 16 + q * 4] = sacc[j][mh];
        __syncthreads();

        // ---- softmax over t: thread handles (n=sn, m=2*sm2, 2*sm2+1)
        {
            float2 v[Tdim];
            float mx0 = -INFINITY, mx1 = -INFINITY;
#pragma unroll
            for (int t = 0; t < Tdim; ++t) {
                v[t] = *(const float2*)&Sb[t][sn][2 * sm2];
                mx0 = fmaxf(mx0, v[t].x); mx1 = fmaxf(mx1, v[t].y);
            }
            float s0 = 0.f, s1 = 0.f;
#pragma unroll
            for (int t = 0; t < Tdim; ++t) {
                v[t].x = expf(v[t].x - mx0); s0 += v[t].x;
                v[t].y = expf(v[t].y - mx1); s1 += v[t].y;
            }
            float i0 = 1.0f / s0, i1 = 1.0f / s1;
#pragma unroll
            for (int t = 0; t < Tdim; ++t) {
                short2 p2 = make_short2(f2bf(v[t].x * i0), f2bf(v[t].y * i1));
                *(short2*)&Pb[t][sn][2 * sm2] = p2;
            }
        }
        __syncthreads();

        // ---- PV
#pragma unroll
        for (int j = 0; j < 3; ++j) {
            int t = w * 3 + j;
            bf16x8 pf = *(const bf16x8*)&Pb[t][l15][q * 8];
#pragma unroll
            for (int ct = 0; ct < 4; ++ct) {
                bf16x8 bfr = *(const bf16x8*)&XT[((size_t)t * Cdim + ct * 16 + l15) * Ndim + m0 + q * 8];
                oacc[j][ct] = __builtin_amdgcn_mfma_f32_16x16x32_bf16(
                    pf, bfr, oacc[j][ct], 0, 0, 0);
            }
        }
    }

    float beta = beta_p[0];
#pragma unroll
    for (int j = 0; j < 3; ++j) {
        int t = w * 3 + j;
#pragma unroll
        for (int ct = 0; ct < 4; ++ct) {
#pragma unroll
            for (int r = 0; r < 4; ++r) {
                size_t idx = (((size_t)b * Tdim + t) * Ndim + n0 + q * 4 + r) * Cdim
                           + ct * 16 + l15;
                Out[idx] += beta * fmaxf(oacc[j][ct][r], 0.f);
            }
        }
    }
}

// ---------------------------------------------------------------- bias = S @ bpool (f32)
__global__ __launch_bounds__(256) void k_bias(
    const short* __restrict__ Sbf, const float* __restrict__ bpool,
    float* __restrict__ bias)
{
    int n0 = blockIdx.x * 16;
    int tid = threadIdx.x;
    int o = tid & 63, rg = tid >> 6;
    float acc[4] = {};
    for (int k = 0; k < 1024; ++k) {
        float bp = bpool[(size_t)k * 64 + o];
#pragma unroll
        for (int r = 0; r < 4; ++r)
            acc[r] += bf2f(Sbf[(size_t)(n0 + rg + r * 4) * 1024 + k]) * bp;
    }
#pragma unroll
    for (int r = 0; r < 4; ++r)
        bias[(size_t)(n0 + rg + r * 4) * 64 + o] = acc[r];
}

// ---------------------------------------------------------------- gconv via MFMA (6 waves)
__global__ __launch_bounds__(384) void k_gconv(
    const short* __restrict__ xgT, const short* __restrict__ Wb,
    const float* __restrict__ bias, float* __restrict__ Out,
    const float* __restrict__ alpha_p)
{
    __shared__ short Wl[64 * 64];
    int n = blockIdx.x;
    int tid = threadIdx.x;
    // stage W[n] with chunk swizzle: chunk j of row k at position j ^ ((k>>3)&7)
    for (int f = tid; f < 512; f += 384) {
        int k = f >> 3, j = f & 7;
        *(bf16x8*)&Wl[k * 64 + (j ^ ((k >> 3) & 7)) * 8] =
            *(const bf16x8*)&Wb[(size_t)n * IOdim + f * 8];
    }
    __syncthreads();
    int w = tid / 64, l = tid & 63, l15 = l & 15, q = l >> 4;
    f32x4 acc[4];
#pragma unroll
    for (int ct = 0; ct < 4; ++ct) acc[ct] = (f32x4)0.f;
    const short* xr = xgT + (size_t)n * Jdim + (size_t)(w * 16 + l15) * 64;
#pragma unroll
    for (int ks = 0; ks < 2; ++ks) {
        bf16x8 a = *(const bf16x8*)&xr[ks * 32 + q * 8];
        int kb = ks * 32 + q * 8;
        int msk = (kb >> 3) & 7;
#pragma unroll
        for (int ct = 0; ct < 4; ++ct) {
            bf16x8 bfr;
#pragma unroll
            for (int e = 0; e < 8; ++e) {
                int o = ct * 16 + l15;
                bfr[e] = Wl[(kb + e) * 64 + (((o >> 3) ^ msk) * 8) + (o & 7)];
            }
            acc[ct] = __builtin_amdgcn_mfma_f32_16x16x32_bf16(a, bfr, acc[ct], 0, 0, 0);
        }
    }
    float alpha = alpha_p[0];
#pragma unroll
    for (int ct = 0; ct < 4; ++ct) {
        int o = ct * 16 + l15;
        float bo = bias[(size_t)n * 64 + o];
#pragma unroll
        for (int r = 0; r < 4; ++r) {
            int bt = w * 16 + q * 4 + r;
            size_t idx = (size_t)bt * 65536 + (size_t)n * 64 + o;
            Out[idx] += alpha * fmaxf(acc[ct][r] + bo, 0.f);
        }
    }
}

// ---------------------------------------------------------------- launch
extern "C" void kernel_launch(void* const* d_in, const int* in_sizes, int n_in,
                              void* d_out, int out_size, void* d_ws, size_t ws_size,
                              hipStream_t stream)
{
    const float* x     = (const float*)d_in[0];
    const float* e1    = (const float*)d_in[1];
    const float* e2    = (const float*)d_in[2];
    const float* Asym  = (const float*)d_in[3];
    const float* wpool = (const float*)d_in[4];
    const float* bpool = (const float*)d_in[5];
    const float* alpha = (const float*)d_in[6];
    const float* beta  = (const float*)d_in[7];
    const float* gamma = (const float*)d_in[8];
    float* out = (float*)d_out;

    short* ASbf = (short*)d_ws;                       // 2048x1024   (4 MB)
    short* xbf  = ASbf + 2048 * 1024;                 // 12.6 MB
    short* xT   = xbf  + 6291456;                     // 12.6 MB
    short* wpT  = xT   + 6291456;                     // 8.4 MB
    short* Wbf  = wpT  + 4194304;                     // 8.4 MB
    short* xgT  = Wbf  + 4194304;                     // 12.6 MB
    float* bias = (float*)(xgT + 6291456);            // 256 KB

    k_supports<<<4096, 256, 0, stream>>>(e1, e2, ASbf + 1024 * 1024);
    k_softmax_rows<<<1024, 256, 0, stream>>>(Asym, ASbf);
    k_cvt_x<<<dim3(16, 96), 256, 0, stream>>>(x, xbf, xT);
    k_cvt_wp<<<dim3(64, 16), 256, 0, stream>>>(wpool, wpT);
    // stacked: rows 0..1023 -> out = gamma*relu(A@x); rows 1024..2047 -> xgT = S@x
    k_gemm_bt<0><<<dim3(16, 48), 256, 0, stream>>>(ASbf, xT, out, xgT, gamma);
    // Wbf = S @ wpool
    k_gemm_bt<1><<<dim3(8, 32), 256, 0, stream>>>(ASbf + 1024 * 1024, wpT, nullptr, Wbf, nullptr);
    k_bias<<<64, 256, 0, stream>>>(ASbf + 1024 * 1024, bpool, bias);
    // out += beta * relu(x_sa)
    k_sa_mfma<<<dim3(Bdim, Ndim / NT2), 256, 0, stream>>>(xbf, xT, out, beta);
    // out += alpha * relu(xgT @ W[n] + bias[n])
    k_gconv<<<1024, 384, 0, stream>>>(xgT, Wbf, bias, out, alpha);
}